// Round 4
// baseline (60.465 us; speedup 1.0000x reference)
//
#include <hip/hip_runtime.h>

// HONU order-2, L=64: out[i] = b + sum_{j<=k} W[woff(j)+k-j] * x[i,j] * x[i,k]
// woff(j) = 64j - j(j-1)/2  (lex order of combinations_with_replacement)
//
// R4: 256 blocks x 1024 threads (16 waves = 4/SIMD; grid is pinned at 256 by
// the lane=row, 64-rows-per-block geometry). X-tile staged in LDS chunk-major
// (tile4[q][row], aligned ds_read_b128 at base+lane*16, conflict-free).
// The (j,k) triangle is 2D-TILED into 16 near-equal compile-time tiles:
//   waves 0-11: off-diagonal half-tiles, j in [J0,J0+8) x k in [K0,K0+16)
//               (128 pairs each; needs only 6 x-chunks = 24 floats)
//   waves 12-15: diagonal tiles A: j,k in [16A,16A+16), k>=j
//               (136 pairs each; needs 4 x-chunks = 16 floats)
// vs R3's suffix split this cuts per-block LDS read traffic ~204KB -> ~95KB
// and live VGPRs ~80 -> ~45. W indices stay compile-time -> SGPR operands.

#define ROWS 64
#define WOFF(j) ((j) * 64 - ((j) * ((j) - 1)) / 2)

template <int Q>
__device__ __forceinline__ void load_chunk(float (&x)[64],
                                           const float4* __restrict__ tile4,
                                           int lane) {
  float4 v = tile4[Q * 64 + lane];  // aligned ds_read_b128
  x[4 * Q + 0] = v.x;
  x[4 * Q + 1] = v.y;
  x[4 * Q + 2] = v.z;
  x[4 * Q + 3] = v.w;
}

// Off-diagonal half-tile: j in [J0, J0+8), k in [K0, K0+16), K0 >= J0+8 range
template <int J0, int K0>
__device__ __forceinline__ float offdiag_work(const float* __restrict__ W,
                                              const float4* __restrict__ tile4,
                                              int lane) {
  float x[64];
  load_chunk<J0 / 4 + 0>(x, tile4, lane);
  load_chunk<J0 / 4 + 1>(x, tile4, lane);
  load_chunk<K0 / 4 + 0>(x, tile4, lane);
  load_chunk<K0 / 4 + 1>(x, tile4, lane);
  load_chunk<K0 / 4 + 2>(x, tile4, lane);
  load_chunk<K0 / 4 + 3>(x, tile4, lane);
  float acc = 0.0f;
#pragma unroll
  for (int j = J0; j < J0 + 8; ++j) {
    const int base = WOFF(j);
    float y = 0.0f;
#pragma unroll
    for (int k = K0; k < K0 + 16; ++k) {
      y = __builtin_fmaf(W[base + (k - j)], x[k], y);
    }
    acc = __builtin_fmaf(x[j], y, acc);
  }
  return acc;
}

// Diagonal tile A: j,k in [16A, 16A+16), k >= j
template <int A>
__device__ __forceinline__ float diag_work(const float* __restrict__ W,
                                           const float4* __restrict__ tile4,
                                           int lane) {
  float x[64];
  load_chunk<4 * A + 0>(x, tile4, lane);
  load_chunk<4 * A + 1>(x, tile4, lane);
  load_chunk<4 * A + 2>(x, tile4, lane);
  load_chunk<4 * A + 3>(x, tile4, lane);
  float acc = 0.0f;
#pragma unroll
  for (int j = 16 * A; j < 16 * A + 16; ++j) {
    const int base = WOFF(j);
    float y = 0.0f;
#pragma unroll
    for (int k = j; k < 16 * A + 16; ++k) {
      y = __builtin_fmaf(W[base + (k - j)], x[k], y);
    }
    acc = __builtin_fmaf(x[j], y, acc);
  }
  return acc;
}

__global__ __launch_bounds__(1024, 4) void honu_kernel(
    const float* __restrict__ X, const float* __restrict__ W,
    const float* __restrict__ Bias, float* __restrict__ out, int nrows) {
  __shared__ float4 tile4[16 * ROWS];  // chunk-major: [q][row], 16 KB
  __shared__ float part[16][64];       // 4 KB

  const int tid = threadIdx.x;
  const int lane = tid & 63;
  const int wave = tid >> 6;
  const int row0 = blockIdx.x * ROWS;

  // Coalesced staging: thread tid loads float4 (row r = tid>>4, chunk q =
  // tid&15) from global, stores chunk-major.
  {
    const int r = tid >> 4;
    const int q = tid & 15;
    float4 v = make_float4(0.f, 0.f, 0.f, 0.f);
    if (row0 + r < nrows) {
      v = reinterpret_cast<const float4*>(X)[(size_t)(row0 + r) * 16 + q];
    }
    tile4[q * 64 + r] = v;
  }
  __syncthreads();

  float acc = 0.0f;
  // 16-way compile-time tiling of the triangle (wave-uniform dispatch).
  // Off-diag 16x16 blocks (a,b), a<b: (0,1)(0,2)(0,3)(1,2)(1,3)(2,3),
  // each split into j-halves; diagonals A=0..3.
  switch (wave) {
    case 0:  acc = offdiag_work<0, 16>(W, tile4, lane);  break;
    case 1:  acc = offdiag_work<8, 16>(W, tile4, lane);  break;
    case 2:  acc = offdiag_work<0, 32>(W, tile4, lane);  break;
    case 3:  acc = offdiag_work<8, 32>(W, tile4, lane);  break;
    case 4:  acc = offdiag_work<0, 48>(W, tile4, lane);  break;
    case 5:  acc = offdiag_work<8, 48>(W, tile4, lane);  break;
    case 6:  acc = offdiag_work<16, 32>(W, tile4, lane); break;
    case 7:  acc = offdiag_work<24, 32>(W, tile4, lane); break;
    case 8:  acc = offdiag_work<16, 48>(W, tile4, lane); break;
    case 9:  acc = offdiag_work<24, 48>(W, tile4, lane); break;
    case 10: acc = offdiag_work<32, 48>(W, tile4, lane); break;
    case 11: acc = offdiag_work<40, 48>(W, tile4, lane); break;
    case 12: acc = diag_work<0>(W, tile4, lane);         break;
    case 13: acc = diag_work<1>(W, tile4, lane);         break;
    case 14: acc = diag_work<2>(W, tile4, lane);         break;
    default: acc = diag_work<3>(W, tile4, lane);         break;
  }
  part[wave][lane] = acc;
  __syncthreads();

  if (tid < 64) {
    const int orow = row0 + tid;
    if (orow < nrows) {
      float r = Bias[0];
#pragma unroll
      for (int w = 0; w < 16; ++w) r += part[w][tid];
      out[orow] = r;
    }
  }
}

extern "C" void kernel_launch(void* const* d_in, const int* in_sizes, int n_in,
                              void* d_out, int out_size, void* d_ws,
                              size_t ws_size, hipStream_t stream) {
  const float* X = (const float*)d_in[0];     // (16384, 64) fp32
  const float* W = (const float*)d_in[1];     // (2145,) fp32 (first 2080 used)
  const float* Bias = (const float*)d_in[2];  // (1,) fp32
  float* out = (float*)d_out;                 // (16384,) fp32

  const int nrows = out_size;  // 16384
  const int grid = (nrows + ROWS - 1) / ROWS;
  honu_kernel<<<grid, 1024, 0, stream>>>(X, W, Bias, out, nrows);
}